// Round 1
// baseline (430.310 us; speedup 1.0000x reference)
//
#include <hip/hip_runtime.h>
#include <cstdint>
#include <cstddef>

#define B_    16
#define C_    256
#define HW_   64
#define N_    4096      // 64*64 spatial
#define K_    512
#define NROW_ 65536     // B_*N_

typedef __attribute__((ext_vector_type(8))) __bf16 bf16x8;
typedef __attribute__((ext_vector_type(4))) float floatx4;

struct P2 { float v1; int k1; float v2; int k2; };

__device__ __forceinline__ bool lexless(float v, int k, float bv, int bk) {
    return (v < bv) || (v == bv && k < bk);
}
__device__ __forceinline__ void ins2(float v, int k, float& v1, int& k1, float& v2, int& k2) {
    if (lexless(v, k, v1, k1)) { v2 = v1; k2 = k1; v1 = v; k1 = k; }
    else if (lexless(v, k, v2, k2)) { v2 = v; k2 = k; }
}

// Bpack layout: [ct 8][plane 2][cq 4][n 512][i 8] bf16, 512 KB.
// Element (ct,plane,cq,n,i) = channel ct*32+cq*8+i of code n, hi/lo split.

// ---------------- kernel 1: codebook prep: e2 + packed bf16 hi/lo tiles -------
__global__ void prep_kernel(const float* __restrict__ cb, float* __restrict__ e2,
                            __bf16* __restrict__ Bpack, double* __restrict__ lossAcc) {
    int n = blockIdx.x, t = threadIdx.x;
    if (n == 0 && t == 0) *lossAcc = 0.0;
    float4 v = *(const float4*)(cb + (size_t)n * C_ + t * 4);
    float vv[4] = {v.x, v.y, v.z, v.w};
    __bf16 h[4], l[4];
    float s = 0.f;
    #pragma unroll
    for (int i = 0; i < 4; ++i) {
        h[i] = (__bf16)vv[i];
        l[i] = (__bf16)(vv[i] - (float)h[i]);
        s = fmaf(vv[i], vv[i], s);
    }
    // c = t*4 + j:  ct = t>>3, cq = (t>>1)&3, i0 = (t&1)*4
    int ct = t >> 3, cq = (t >> 1) & 3, i0 = (t & 1) * 4;
    size_t base = (size_t)ct * 32768;
    size_t off0 = base + ((size_t)(0 * 4 + cq) * 512 + n) * 8 + i0;   // hi plane
    size_t off1 = base + ((size_t)(1 * 4 + cq) * 512 + n) * 8 + i0;   // lo plane
    *(ushort4*)&Bpack[off0] = *(ushort4*)h;
    *(ushort4*)&Bpack[off1] = *(ushort4*)l;
    #pragma unroll
    for (int off = 32; off; off >>= 1) s += __shfl_down(s, off);
    if (t == 0) e2[n] = s;
}

// ---------------- kernel 2: split-bf16 MFMA GEMM + per-row top-2 over 512 -----
// grid 1024; block 512 (8 waves). Tile: 64 rows x ALL 512 codes (wave owns 64).
// B: per-wave register loads from L2-hot Bpack (disjoint slices -> no staging,
//    no DMA, no vmcnt(0) drain). A: LDS double-buffered, prefetch depth 2,
//    ONE __syncthreads per K-step.
__launch_bounds__(512, 4)
__global__ void main_kernel(const float* __restrict__ pq,
                            const __bf16* __restrict__ Bpack,
                            const float* __restrict__ e2, P2* __restrict__ partials,
                            float* __restrict__ x2) {
    const int Mtile = blockIdx.x;
    const int tid  = threadIdx.x;
    const int wave = tid >> 6, lane = tid & 63;
    const int lm = lane & 15, quad = lane >> 4;
    const int b  = Mtile >> 6;
    const int s0 = (Mtile * 64) & 4095;

    __shared__ __bf16 As[2][2][64][40];   // [buf][plane][row][ch'] pad-40, 20.5 KB
    __shared__ float  xs[8][64];
    __shared__ P2     mb[8][64];          // 8 KB cross-wave merge

    floatx4 acc[4][4];                    // [mt][nt] -> 64 VGPRs
    #pragma unroll
    for (int i = 0; i < 4; ++i)
        #pragma unroll
        for (int j = 0; j < 4; ++j) acc[i][j] = (floatx4)0.f;

    const float* pqA = pq + (size_t)b * (C_ * N_) + s0 + lane;
    float x2loc = 0.f;
    float aA[4], aB[4];                   // A prefetch regs, alternating tiles

    // thread (wave,lane): channels T*32 + wave*4 + i, spatial s0+lane
    #define LOADA(R, T) { _Pragma("unroll") \
        for (int i = 0; i < 4; ++i) \
            R[i] = pqA[(size_t)((T) * 32 + wave * 4 + i) * N_]; }
    #define CVTST(R, BUF) { __bf16 h_[4], l_[4]; _Pragma("unroll") \
        for (int i = 0; i < 4; ++i) { float a_ = R[i]; h_[i] = (__bf16)a_; \
            l_[i] = (__bf16)(a_ - (float)h_[i]); x2loc = fmaf(a_, a_, x2loc); } \
        *(ushort4*)&As[BUF][0][lane][wave * 4] = *(ushort4*)h_; \
        *(ushort4*)&As[BUF][1][lane][wave * 4] = *(ushort4*)l_; }

    LOADA(aA, 0)
    CVTST(aA, 0)
    LOADA(aB, 1)
    __syncthreads();                      // As[0] visible

    #pragma unroll
    for (int ct = 0; ct < 8; ++ct) {
        const int cur = ct & 1;
        // ---- issue A prefetch (tile ct+2) first: barrier drain lands late ----
        if (ct < 6) { if (cur == 0) { LOADA(aA, ct + 2) } else { LOADA(aB, ct + 2) } }
        // ---- convert+store A tile ct+1 into the other buffer ----
        if (ct < 7) { if (cur == 0) { CVTST(aB, 1) } else { CVTST(aA, 0) } }

        // ---- B hi fragments: wave's 64 codes, channels ct*32+quad*8.. ----
        const __bf16* bp = Bpack + (size_t)ct * 32768
                         + ((size_t)quad * 512 + wave * 64 + lm) * 8;
        bf16x8 bh[4];
        #pragma unroll
        for (int nt = 0; nt < 4; ++nt)
            bh[nt] = *(const bf16x8*)(bp + (size_t)nt * 128);

        // ---- A hi fragments from LDS ----
        bf16x8 a1[4];
        #pragma unroll
        for (int mt = 0; mt < 4; ++mt)
            a1[mt] = *(const bf16x8*)&As[cur][0][mt * 16 + lm][quad * 8];

        // pass1: a_hi * b_hi
        #pragma unroll
        for (int nt = 0; nt < 4; ++nt)
            #pragma unroll
            for (int mt = 0; mt < 4; ++mt)
                acc[mt][nt] = __builtin_amdgcn_mfma_f32_16x16x32_bf16(a1[mt], bh[nt], acc[mt][nt], 0, 0, 0);
        // pass2: a_hi * b_lo (b_lo transient)
        #pragma unroll
        for (int nt = 0; nt < 4; ++nt) {
            bf16x8 bl = *(const bf16x8*)(bp + 16384 + (size_t)nt * 128);
            #pragma unroll
            for (int mt = 0; mt < 4; ++mt)
                acc[mt][nt] = __builtin_amdgcn_mfma_f32_16x16x32_bf16(a1[mt], bl, acc[mt][nt], 0, 0, 0);
        }
        // pass3: a_lo * b_hi (a_lo transient)
        #pragma unroll
        for (int mt = 0; mt < 4; ++mt) {
            bf16x8 a2 = *(const bf16x8*)&As[cur][1][mt * 16 + lm][quad * 8];
            #pragma unroll
            for (int nt = 0; nt < 4; ++nt)
                acc[mt][nt] = __builtin_amdgcn_mfma_f32_16x16x32_bf16(a2, bh[nt], acc[mt][nt], 0, 0, 0);
        }
        __syncthreads();   // As[cur] reads done / As[cur^1] writes visible
    }

    xs[wave][lane] = x2loc;

    // ---- epilogue: per-wave top-2 over its 64 codes -> 8-way LDS merge ----
    const int kbase = wave * 64;
    float e2v[4];
    #pragma unroll
    for (int nt = 0; nt < 4; ++nt) e2v[nt] = e2[kbase + nt * 16 + lm];

    #pragma unroll
    for (int mt = 0; mt < 4; ++mt) {
        #pragma unroll
        for (int r = 0; r < 4; ++r) {
            float v1 = __builtin_inff(), v2 = __builtin_inff();
            int k1 = 0x7fffffff, k2 = 0x7fffffff;
            #pragma unroll
            for (int nt = 0; nt < 4; ++nt) {
                float v = fmaf(-2.f, acc[mt][nt][r], e2v[nt]);
                ins2(v, kbase + nt * 16 + lm, v1, k1, v2, k2);
            }
            #pragma unroll
            for (int m = 1; m < 16; m <<= 1) {
                float ov1 = __shfl_xor(v1, m); int ok1 = __shfl_xor(k1, m);
                float ov2 = __shfl_xor(v2, m); int ok2 = __shfl_xor(k2, m);
                ins2(ov1, ok1, v1, k1, v2, k2);
                ins2(ov2, ok2, v1, k1, v2, k2);
            }
            if (lm == 0) {
                P2 p; p.v1 = v1; p.k1 = k1; p.v2 = v2; p.k2 = k2;
                mb[wave][mt * 16 + quad * 4 + r] = p;
            }
        }
    }
    __syncthreads();

    if (tid < 64) {
        float v1 = __builtin_inff(), v2 = __builtin_inff();
        int k1 = 0x7fffffff, k2 = 0x7fffffff;
        float xsum = 0.f;
        #pragma unroll
        for (int w = 0; w < 8; ++w) {
            P2 p = mb[w][tid];
            ins2(p.v1, p.k1, v1, k1, v2, k2);
            ins2(p.v2, p.k2, v1, k1, v2, k2);
            xsum += xs[w][tid];
        }
        P2 p; p.v1 = v1; p.k1 = k1; p.v2 = v2; p.k2 = k2;
        partials[Mtile * 64 + tid] = p;
        x2[Mtile * 64 + tid] = xsum;
    }
}

// ---------------- kernel 3: fused refine + loss + gather ----------------------
// Output flat position p uses the winner of query row sigma(p) (H/W swap).
#define MARGIN 0.05f
__global__ void scatter_merge_kernel(const P2* __restrict__ partials,
                                     const float* __restrict__ x2arr,
                                     const float* __restrict__ pq,
                                     const float* __restrict__ cb,
                                     double* __restrict__ lossAcc,
                                     float* __restrict__ out) {
    int ntile = blockIdx.x, b = blockIdx.y, tid = threadIdx.x;
    int wave = tid >> 6;
    __shared__ int idxs[64];
    __shared__ double lred[4];
    __shared__ float tile[64][65];

    double myloss = 0.0;
    if (tid < 64) {
        int p = ntile * 64 + tid;                       // output flat spatial pos
        int s = ((p & 63) << 6) | (p >> 6);             // sigma (involution)
        int row = (b << 12) | s;
        P2 pp = partials[row];
        float v1 = pp.v1, v2 = pp.v2;
        int k1 = pp.k1, k2 = pp.k2;
        int kwin = k1;
        double d2min;
        if (v2 - v1 < MARGIN) {
            const float* xp  = pq + (size_t)b * (C_ * N_) + s;
            const float* ca  = cb + (size_t)k1 * C_;
            const float* cbp = cb + (size_t)k2 * C_;
            double da = 0.0, db = 0.0;
            for (int c = 0; c < C_; ++c) {
                double xv = (double)xp[(size_t)c * N_];
                double ea = xv - (double)ca[c];  da += ea * ea;
                double eb = xv - (double)cbp[c]; db += eb * eb;
            }
            if (db < da || (db == da && k2 < k1)) { kwin = k2; d2min = db; }
            else d2min = da;
        } else {
            d2min = (double)(x2arr[row] + v1);
        }
        idxs[tid] = kwin;
        myloss = d2min;
    }
    double sd = myloss;
    #pragma unroll
    for (int off = 32; off; off >>= 1) sd += __shfl_down(sd, off);
    if ((tid & 63) == 0) lred[wave] = sd;
    __syncthreads();
    if (tid == 0) atomicAdd(lossAcc, lred[0] + lred[1] + lred[2] + lred[3]);

    for (int cc = 0; cc < 4; ++cc) {
        int c0 = cc * 64;
        #pragma unroll
        for (int pp = 0; pp < 16; ++pp) {
            int i = pp * 4 + (tid >> 6);
            int c = tid & 63;
            tile[i][c] = cb[(size_t)idxs[i] * C_ + c0 + c];   // coalesced rows
        }
        __syncthreads();
        #pragma unroll
        for (int pp = 0; pp < 16; ++pp) {
            int cl = pp * 4 + (tid >> 6);
            int nl = tid & 63;
            out[((size_t)(b * C_ + c0 + cl)) * N_ + ntile * 64 + nl] = tile[nl][cl];
        }
        __syncthreads();
    }
}

// ---------------- kernel 4: loss finalize ------------------------------------
__global__ void finalize_kernel(const double* __restrict__ lossAcc, float* __restrict__ out) {
    out[(size_t)B_ * C_ * N_] =
        (float)(1.25 * (*lossAcc) / (double)((size_t)B_ * N_ * C_));
}

// ---------------- launch ------------------------------------------------------
extern "C" void kernel_launch(void* const* d_in, const int* in_sizes, int n_in,
                              void* d_out, int out_size, void* d_ws, size_t ws_size,
                              hipStream_t stream) {
    const float* pq = (const float*)d_in[0];   // [16,256,64,64]
    const float* cb = (const float*)d_in[1];   // [512,256]
    float* out = (float*)d_out;                // 4194304 out + 1 loss
    char* ws = (char*)d_ws;
    double* lossAcc = (double*)ws;                            // 16 B
    float*  e2    = (float*)(ws + 16);                        // 2 KB
    float*  x2    = (float*)(ws + 16 + 2048);                 // 256 KB
    __bf16* Bpack = (__bf16*)(ws + 16 + 2048 + 262144);       // 512 KB
    P2* partials  = (P2*)(ws + 16 + 2048 + 262144 + 524288);  // 1 MB

    prep_kernel<<<K_, 64, 0, stream>>>(cb, e2, Bpack, lossAcc);
    main_kernel<<<1024, 512, 0, stream>>>(pq, Bpack, e2, partials, x2);
    scatter_merge_kernel<<<dim3(HW_, B_), 256, 0, stream>>>(partials, x2, pq, cb, lossAcc, out);
    finalize_kernel<<<1, 1, 0, stream>>>(lossAcc, out);
}

// Round 2
// 430.129 us; speedup vs baseline: 1.0004x; 1.0004x over previous
//
#include <hip/hip_runtime.h>
#include <cstdint>
#include <cstddef>

#define B_    16
#define C_    256
#define HW_   64
#define N_    4096      // 64*64 spatial
#define K_    512
#define NROW_ 65536     // B_*N_

typedef __attribute__((ext_vector_type(8))) __bf16 bf16x8;
typedef __attribute__((ext_vector_type(4))) float floatx4;

struct P2 { float v1; int k1; float v2; int k2; };

__device__ __forceinline__ bool lexless(float v, int k, float bv, int bk) {
    return (v < bv) || (v == bv && k < bk);
}
__device__ __forceinline__ void ins2(float v, int k, float& v1, int& k1, float& v2, int& k2) {
    if (lexless(v, k, v1, k1)) { v2 = v1; k2 = k1; v1 = v; k1 = k; }
    else if (lexless(v, k, v2, k2)) { v2 = v; k2 = k; }
}

// Bpack layout: [ct 8][plane 2][cq 4][n 512][i 8] bf16, 512 KB.
// Element (ct,plane,cq,n,i) = channel ct*32+cq*8+i of code n, hi/lo split.

// ---------------- kernel 1: codebook prep: e2 + packed bf16 hi/lo tiles -------
__global__ void prep_kernel(const float* __restrict__ cb, float* __restrict__ e2,
                            __bf16* __restrict__ Bpack, double* __restrict__ lossAcc) {
    int n = blockIdx.x, t = threadIdx.x;
    if (n == 0 && t == 0) *lossAcc = 0.0;
    float4 v = *(const float4*)(cb + (size_t)n * C_ + t * 4);
    float vv[4] = {v.x, v.y, v.z, v.w};
    __bf16 h[4], l[4];
    float s = 0.f;
    #pragma unroll
    for (int i = 0; i < 4; ++i) {
        h[i] = (__bf16)vv[i];
        l[i] = (__bf16)(vv[i] - (float)h[i]);
        s = fmaf(vv[i], vv[i], s);
    }
    // c = t*4 + j:  ct = t>>3, cq = (t>>1)&3, i0 = (t&1)*4
    int ct = t >> 3, cq = (t >> 1) & 3, i0 = (t & 1) * 4;
    size_t base = (size_t)ct * 32768;
    size_t off0 = base + ((size_t)(0 * 4 + cq) * 512 + n) * 8 + i0;   // hi plane
    size_t off1 = base + ((size_t)(1 * 4 + cq) * 512 + n) * 8 + i0;   // lo plane
    *(ushort4*)&Bpack[off0] = *(ushort4*)h;
    *(ushort4*)&Bpack[off1] = *(ushort4*)l;
    #pragma unroll
    for (int off = 32; off; off >>= 1) s += __shfl_down(s, off);
    if (t == 0) e2[n] = s;
}

// ---------------- kernel 2: split-bf16 MFMA GEMM + per-row top-2 over 512 -----
// grid 1024; block 512 (8 waves). Tile: 64 rows x ALL 512 codes (wave owns 64).
// A: ALL 32 f32/thread loaded in the PROLOGUE (independent, coalesced; latency
//    paid once, hidden by TLP), held as bf16 hi/lo in 32 VGPRs. K-loop has ZERO
//    global A traffic: ds_write next tile from regs, one barrier per K-step.
// B: per-wave register loads from L2-hot Bpack (disjoint 64-code slices).
//    In-loop vmcnt queue contains ONLY B loads.
__launch_bounds__(512, 4)
__global__ void main_kernel(const float* __restrict__ pq,
                            const __bf16* __restrict__ Bpack,
                            const float* __restrict__ e2, P2* __restrict__ partials,
                            float* __restrict__ x2) {
    const int Mtile = blockIdx.x;
    const int tid  = threadIdx.x;
    const int wave = tid >> 6, lane = tid & 63;
    const int lm = lane & 15, quad = lane >> 4;
    const int b  = Mtile >> 6;
    const int s0 = (Mtile * 64) & 4095;

    __shared__ __attribute__((aligned(16))) __bf16 As[2][2][64][40]; // 20.5 KB
    __shared__ float  xs[8][64];
    __shared__ P2     mb[8][64];          // 8 KB cross-wave merge

    floatx4 acc[4][4];                    // [mt][nt]
    #pragma unroll
    for (int i = 0; i < 4; ++i)
        #pragma unroll
        for (int j = 0; j < 4; ++j) acc[i][j] = (floatx4)0.f;

    // ---- prologue: load ALL of this thread's A (32 independent coalesced loads)
    const float* pqA = pq + (size_t)b * (C_ * N_) + s0 + lane;
    float af[8][4];
    #pragma unroll
    for (int ct = 0; ct < 8; ++ct)
        #pragma unroll
        for (int i = 0; i < 4; ++i)
            af[ct][i] = pqA[(size_t)(ct * 32 + wave * 4 + i) * N_];

    float x2loc = 0.f;
    ushort4 hA[8], lA[8];                 // packed bf16 hi/lo, 32 VGPRs
    #pragma unroll
    for (int ct = 0; ct < 8; ++ct) {
        __bf16 h[4], l[4];
        #pragma unroll
        for (int i = 0; i < 4; ++i) {
            float a = af[ct][i];
            h[i] = (__bf16)a;
            l[i] = (__bf16)(a - (float)h[i]);
            x2loc = fmaf(a, a, x2loc);
        }
        hA[ct] = *(ushort4*)h;
        lA[ct] = *(ushort4*)l;
    }
    xs[wave][lane] = x2loc;

    // tile 0 into buf 0
    *(ushort4*)&As[0][0][lane][wave * 4] = hA[0];
    *(ushort4*)&As[0][1][lane][wave * 4] = lA[0];
    __syncthreads();

    #pragma unroll
    for (int ct = 0; ct < 8; ++ct) {
        const int cur = ct & 1;
        // ---- stage tile ct+1 from registers (no latency) ----
        if (ct < 7) {
            *(ushort4*)&As[cur ^ 1][0][lane][wave * 4] = hA[ct + 1];
            *(ushort4*)&As[cur ^ 1][1][lane][wave * 4] = lA[ct + 1];
        }

        // ---- B fragments: wave's 64 codes, channels ct*32+quad*8.. ----
        const __bf16* bp = Bpack + (size_t)ct * 32768
                         + ((size_t)quad * 512 + wave * 64 + lm) * 8;
        bf16x8 bh[4], bl[4];
        #pragma unroll
        for (int nt = 0; nt < 4; ++nt) {
            bh[nt] = *(const bf16x8*)(bp + (size_t)nt * 128);
            bl[nt] = *(const bf16x8*)(bp + 16384 + (size_t)nt * 128);
        }

        // ---- A fragments from LDS ----
        bf16x8 a1[4], a2[4];
        #pragma unroll
        for (int mt = 0; mt < 4; ++mt) {
            a1[mt] = *(const bf16x8*)&As[cur][0][mt * 16 + lm][quad * 8];
            a2[mt] = *(const bf16x8*)&As[cur][1][mt * 16 + lm][quad * 8];
        }

        // pass1: a_hi * b_hi
        #pragma unroll
        for (int nt = 0; nt < 4; ++nt)
            #pragma unroll
            for (int mt = 0; mt < 4; ++mt)
                acc[mt][nt] = __builtin_amdgcn_mfma_f32_16x16x32_bf16(a1[mt], bh[nt], acc[mt][nt], 0, 0, 0);
        // pass2: a_hi * b_lo
        #pragma unroll
        for (int nt = 0; nt < 4; ++nt)
            #pragma unroll
            for (int mt = 0; mt < 4; ++mt)
                acc[mt][nt] = __builtin_amdgcn_mfma_f32_16x16x32_bf16(a1[mt], bl[nt], acc[mt][nt], 0, 0, 0);
        // pass3: a_lo * b_hi
        #pragma unroll
        for (int mt = 0; mt < 4; ++mt)
            #pragma unroll
            for (int nt = 0; nt < 4; ++nt)
                acc[mt][nt] = __builtin_amdgcn_mfma_f32_16x16x32_bf16(a2[mt], bh[nt], acc[mt][nt], 0, 0, 0);

        __syncthreads();   // As[cur] reads done / As[cur^1] writes visible
    }

    // ---- epilogue: per-wave top-2 over its 64 codes -> 8-way LDS merge ----
    const int kbase = wave * 64;
    float e2v[4];
    #pragma unroll
    for (int nt = 0; nt < 4; ++nt) e2v[nt] = e2[kbase + nt * 16 + lm];

    #pragma unroll
    for (int mt = 0; mt < 4; ++mt) {
        #pragma unroll
        for (int r = 0; r < 4; ++r) {
            float v1 = __builtin_inff(), v2 = __builtin_inff();
            int k1 = 0x7fffffff, k2 = 0x7fffffff;
            #pragma unroll
            for (int nt = 0; nt < 4; ++nt) {
                float v = fmaf(-2.f, acc[mt][nt][r], e2v[nt]);
                ins2(v, kbase + nt * 16 + lm, v1, k1, v2, k2);
            }
            #pragma unroll
            for (int m = 1; m < 16; m <<= 1) {
                float ov1 = __shfl_xor(v1, m); int ok1 = __shfl_xor(k1, m);
                float ov2 = __shfl_xor(v2, m); int ok2 = __shfl_xor(k2, m);
                ins2(ov1, ok1, v1, k1, v2, k2);
                ins2(ov2, ok2, v1, k1, v2, k2);
            }
            if (lm == 0) {
                P2 p; p.v1 = v1; p.k1 = k1; p.v2 = v2; p.k2 = k2;
                mb[wave][mt * 16 + quad * 4 + r] = p;
            }
        }
    }
    __syncthreads();

    if (tid < 64) {
        float v1 = __builtin_inff(), v2 = __builtin_inff();
        int k1 = 0x7fffffff, k2 = 0x7fffffff;
        float xsum = 0.f;
        #pragma unroll
        for (int w = 0; w < 8; ++w) {
            P2 p = mb[w][tid];
            ins2(p.v1, p.k1, v1, k1, v2, k2);
            ins2(p.v2, p.k2, v1, k1, v2, k2);
            xsum += xs[w][tid];
        }
        P2 p; p.v1 = v1; p.k1 = k1; p.v2 = v2; p.k2 = k2;
        partials[Mtile * 64 + tid] = p;
        x2[Mtile * 64 + tid] = xsum;
    }
}

// ---------------- kernel 3: fused refine + loss + gather ----------------------
// Output flat position p uses the winner of query row sigma(p) (H/W swap).
#define MARGIN 0.05f
__global__ void scatter_merge_kernel(const P2* __restrict__ partials,
                                     const float* __restrict__ x2arr,
                                     const float* __restrict__ pq,
                                     const float* __restrict__ cb,
                                     double* __restrict__ lossAcc,
                                     float* __restrict__ out) {
    int ntile = blockIdx.x, b = blockIdx.y, tid = threadIdx.x;
    int wave = tid >> 6;
    __shared__ int idxs[64];
    __shared__ double lred[4];
    __shared__ float tile[64][65];

    double myloss = 0.0;
    if (tid < 64) {
        int p = ntile * 64 + tid;                       // output flat spatial pos
        int s = ((p & 63) << 6) | (p >> 6);             // sigma (involution)
        int row = (b << 12) | s;
        P2 pp = partials[row];
        float v1 = pp.v1, v2 = pp.v2;
        int k1 = pp.k1, k2 = pp.k2;
        int kwin = k1;
        double d2min;
        if (v2 - v1 < MARGIN) {
            const float* xp  = pq + (size_t)b * (C_ * N_) + s;
            const float* ca  = cb + (size_t)k1 * C_;
            const float* cbp = cb + (size_t)k2 * C_;
            double da = 0.0, db = 0.0;
            for (int c = 0; c < C_; ++c) {
                double xv = (double)xp[(size_t)c * N_];
                double ea = xv - (double)ca[c];  da += ea * ea;
                double eb = xv - (double)cbp[c]; db += eb * eb;
            }
            if (db < da || (db == da && k2 < k1)) { kwin = k2; d2min = db; }
            else d2min = da;
        } else {
            d2min = (double)(x2arr[row] + v1);
        }
        idxs[tid] = kwin;
        myloss = d2min;
    }
    double sd = myloss;
    #pragma unroll
    for (int off = 32; off; off >>= 1) sd += __shfl_down(sd, off);
    if ((tid & 63) == 0) lred[wave] = sd;
    __syncthreads();
    if (tid == 0) atomicAdd(lossAcc, lred[0] + lred[1] + lred[2] + lred[3]);

    for (int cc = 0; cc < 4; ++cc) {
        int c0 = cc * 64;
        #pragma unroll
        for (int pp = 0; pp < 16; ++pp) {
            int i = pp * 4 + (tid >> 6);
            int c = tid & 63;
            tile[i][c] = cb[(size_t)idxs[i] * C_ + c0 + c];   // coalesced rows
        }
        __syncthreads();
        #pragma unroll
        for (int pp = 0; pp < 16; ++pp) {
            int cl = pp * 4 + (tid >> 6);
            int nl = tid & 63;
            out[((size_t)(b * C_ + c0 + cl)) * N_ + ntile * 64 + nl] = tile[nl][cl];
        }
        __syncthreads();
    }
}

// ---------------- kernel 4: loss finalize ------------------------------------
__global__ void finalize_kernel(const double* __restrict__ lossAcc, float* __restrict__ out) {
    out[(size_t)B_ * C_ * N_] =
        (float)(1.25 * (*lossAcc) / (double)((size_t)B_ * N_ * C_));
}

// ---------------- launch ------------------------------------------------------
extern "C" void kernel_launch(void* const* d_in, const int* in_sizes, int n_in,
                              void* d_out, int out_size, void* d_ws, size_t ws_size,
                              hipStream_t stream) {
    const float* pq = (const float*)d_in[0];   // [16,256,64,64]
    const float* cb = (const float*)d_in[1];   // [512,256]
    float* out = (float*)d_out;                // 4194304 out + 1 loss
    char* ws = (char*)d_ws;
    double* lossAcc = (double*)ws;                            // 16 B
    float*  e2    = (float*)(ws + 16);                        // 2 KB
    float*  x2    = (float*)(ws + 16 + 2048);                 // 256 KB
    __bf16* Bpack = (__bf16*)(ws + 16 + 2048 + 262144);       // 512 KB
    P2* partials  = (P2*)(ws + 16 + 2048 + 262144 + 524288);  // 1 MB

    prep_kernel<<<K_, 64, 0, stream>>>(cb, e2, Bpack, lossAcc);
    main_kernel<<<1024, 512, 0, stream>>>(pq, Bpack, e2, partials, x2);
    scatter_merge_kernel<<<dim3(HW_, B_), 256, 0, stream>>>(partials, x2, pq, cb, lossAcc, out);
    finalize_kernel<<<1, 1, 0, stream>>>(lossAcc, out);
}

// Round 3
// 427.662 us; speedup vs baseline: 1.0062x; 1.0058x over previous
//
#include <hip/hip_runtime.h>
#include <cstdint>
#include <cstddef>

#define B_    16
#define C_    256
#define HW_   64
#define N_    4096      // 64*64 spatial
#define K_    512
#define NROW_ 65536     // B_*N_

typedef __attribute__((ext_vector_type(8))) __bf16 bf16x8;
typedef __attribute__((ext_vector_type(4))) float floatx4;

struct P2 { float v1; int k1; float v2; int k2; };

__device__ __forceinline__ bool lexless(float v, int k, float bv, int bk) {
    return (v < bv) || (v == bv && k < bk);
}
__device__ __forceinline__ void ins2(float v, int k, float& v1, int& k1, float& v2, int& k2) {
    if (lexless(v, k, v1, k1)) { v2 = v1; k2 = k1; v1 = v; k1 = k; }
    else if (lexless(v, k, v2, k2)) { v2 = v; k2 = k; }
}

// Bpack layout: [ct 8][plane 2][cq 4][n 512][i 8] bf16, 512 KB.
// Element (ct,plane,cq,n,i) = channel ct*32+cq*8+i of code n, hi/lo split.

// ---------------- kernel 1: codebook prep: e2 + packed bf16 hi/lo tiles -------
__global__ void prep_kernel(const float* __restrict__ cb, float* __restrict__ e2,
                            __bf16* __restrict__ Bpack, double* __restrict__ lossAcc) {
    int n = blockIdx.x, t = threadIdx.x;
    if (n == 0 && t == 0) *lossAcc = 0.0;
    float4 v = *(const float4*)(cb + (size_t)n * C_ + t * 4);
    float vv[4] = {v.x, v.y, v.z, v.w};
    __bf16 h[4], l[4];
    float s = 0.f;
    #pragma unroll
    for (int i = 0; i < 4; ++i) {
        h[i] = (__bf16)vv[i];
        l[i] = (__bf16)(vv[i] - (float)h[i]);
        s = fmaf(vv[i], vv[i], s);
    }
    // c = t*4 + j:  ct = t>>3, cq = (t>>1)&3, i0 = (t&1)*4
    int ct = t >> 3, cq = (t >> 1) & 3, i0 = (t & 1) * 4;
    size_t base = (size_t)ct * 32768;
    size_t off0 = base + ((size_t)(0 * 4 + cq) * 512 + n) * 8 + i0;   // hi plane
    size_t off1 = base + ((size_t)(1 * 4 + cq) * 512 + n) * 8 + i0;   // lo plane
    *(ushort4*)&Bpack[off0] = *(ushort4*)h;
    *(ushort4*)&Bpack[off1] = *(ushort4*)l;
    #pragma unroll
    for (int off = 32; off; off >>= 1) s += __shfl_down(s, off);
    if (t == 0) e2[n] = s;
}

// ---------------- kernel 2: split-bf16 MFMA GEMM + per-row top-2 over 512 -----
// grid 1024; block 512 (8 waves). Tile: 64 rows x ALL 512 codes (wave owns 64).
// BARRIER-FREE K-loop: the FULL 256-channel A tile (hi/lo bf16, 65 KB) is
// staged to LDS once in the prologue behind a single __syncthreads. After
// that, every wave streams its disjoint B slice from L2-hot Bpack and reads
// the read-only A LDS with NO synchronization — waves drift apart, so L2
// bursts de-synchronize and co-resident waves hide each other's B latency
// under MFMA issue. (R0-R2 all shared a per-K-step __syncthreads lock-step
// and all stalled ~75% with every pipe idle; this removes that structure.)
__launch_bounds__(512, 4)
__global__ void main_kernel(const float* __restrict__ pq,
                            const __bf16* __restrict__ Bpack,
                            const float* __restrict__ e2, P2* __restrict__ partials,
                            float* __restrict__ x2) {
    const int Mtile = blockIdx.x;
    const int tid  = threadIdx.x;
    const int wave = tid >> 6, lane = tid & 63;
    const int lm = lane & 15, quad = lane >> 4;
    const int b  = Mtile >> 6;
    const int s0 = (Mtile * 64) & 4095;

    __shared__ __attribute__((aligned(16))) __bf16 Afull[2][64][260]; // 65 KB
    __shared__ float  xs[8][64];
    __shared__ P2     mb[8][64];          // 8 KB cross-wave merge

    floatx4 acc[4][4];                    // [mt][nt]
    #pragma unroll
    for (int i = 0; i < 4; ++i)
        #pragma unroll
        for (int j = 0; j < 4; ++j) acc[i][j] = (floatx4)0.f;

    // ---- prologue: load ALL of this thread's A (32 independent coalesced
    //      loads, latency paid once), convert, stage full tile to LDS ----
    const float* pqA = pq + (size_t)b * (C_ * N_) + s0 + lane;
    float af[8][4];
    #pragma unroll
    for (int ct = 0; ct < 8; ++ct)
        #pragma unroll
        for (int i = 0; i < 4; ++i)
            af[ct][i] = pqA[(size_t)(ct * 32 + wave * 4 + i) * N_];

    float x2loc = 0.f;
    #pragma unroll
    for (int ct = 0; ct < 8; ++ct) {
        __bf16 h[4], l[4];
        #pragma unroll
        for (int i = 0; i < 4; ++i) {
            float a = af[ct][i];
            h[i] = (__bf16)a;
            l[i] = (__bf16)(a - (float)h[i]);
            x2loc = fmaf(a, a, x2loc);
        }
        *(ushort4*)&Afull[0][lane][ct * 32 + wave * 4] = *(ushort4*)h;
        *(ushort4*)&Afull[1][lane][ct * 32 + wave * 4] = *(ushort4*)l;
    }
    xs[wave][lane] = x2loc;
    __syncthreads();                      // ONLY barrier before epilogue merge

    // ---- barrier-free K-loop ----
    #pragma unroll
    for (int ct = 0; ct < 8; ++ct) {
        // B fragments: wave's 64 codes, channels ct*32+quad*8..
        const __bf16* bp = Bpack + (size_t)ct * 32768
                         + ((size_t)quad * 512 + wave * 64 + lm) * 8;
        bf16x8 bh[4], bl[4];
        #pragma unroll
        for (int nt = 0; nt < 4; ++nt)
            bh[nt] = *(const bf16x8*)(bp + (size_t)nt * 128);
        #pragma unroll
        for (int nt = 0; nt < 4; ++nt)
            bl[nt] = *(const bf16x8*)(bp + 16384 + (size_t)nt * 128);

        // A hi fragments
        bf16x8 a1[4];
        #pragma unroll
        for (int mt = 0; mt < 4; ++mt)
            a1[mt] = *(const bf16x8*)&Afull[0][mt * 16 + lm][ct * 32 + quad * 8];

        // pass1: a_hi * b_hi
        #pragma unroll
        for (int nt = 0; nt < 4; ++nt)
            #pragma unroll
            for (int mt = 0; mt < 4; ++mt)
                acc[mt][nt] = __builtin_amdgcn_mfma_f32_16x16x32_bf16(a1[mt], bh[nt], acc[mt][nt], 0, 0, 0);
        // pass2: a_hi * b_lo  (a1 dies here -> regs reused for a2)
        #pragma unroll
        for (int nt = 0; nt < 4; ++nt)
            #pragma unroll
            for (int mt = 0; mt < 4; ++mt)
                acc[mt][nt] = __builtin_amdgcn_mfma_f32_16x16x32_bf16(a1[mt], bl[nt], acc[mt][nt], 0, 0, 0);
        // pass3: a_lo * b_hi
        #pragma unroll
        for (int mt = 0; mt < 4; ++mt) {
            bf16x8 a2 = *(const bf16x8*)&Afull[1][mt * 16 + lm][ct * 32 + quad * 8];
            #pragma unroll
            for (int nt = 0; nt < 4; ++nt)
                acc[mt][nt] = __builtin_amdgcn_mfma_f32_16x16x32_bf16(a2, bh[nt], acc[mt][nt], 0, 0, 0);
        }
    }

    // ---- epilogue: per-wave top-2 over its 64 codes -> 8-way LDS merge ----
    const int kbase = wave * 64;
    float e2v[4];
    #pragma unroll
    for (int nt = 0; nt < 4; ++nt) e2v[nt] = e2[kbase + nt * 16 + lm];

    #pragma unroll
    for (int mt = 0; mt < 4; ++mt) {
        #pragma unroll
        for (int r = 0; r < 4; ++r) {
            float v1 = __builtin_inff(), v2 = __builtin_inff();
            int k1 = 0x7fffffff, k2 = 0x7fffffff;
            #pragma unroll
            for (int nt = 0; nt < 4; ++nt) {
                float v = fmaf(-2.f, acc[mt][nt][r], e2v[nt]);
                ins2(v, kbase + nt * 16 + lm, v1, k1, v2, k2);
            }
            #pragma unroll
            for (int m = 1; m < 16; m <<= 1) {
                float ov1 = __shfl_xor(v1, m); int ok1 = __shfl_xor(k1, m);
                float ov2 = __shfl_xor(v2, m); int ok2 = __shfl_xor(k2, m);
                ins2(ov1, ok1, v1, k1, v2, k2);
                ins2(ov2, ok2, v1, k1, v2, k2);
            }
            if (lm == 0) {
                P2 p; p.v1 = v1; p.k1 = k1; p.v2 = v2; p.k2 = k2;
                mb[wave][mt * 16 + quad * 4 + r] = p;
            }
        }
    }
    __syncthreads();

    if (tid < 64) {
        float v1 = __builtin_inff(), v2 = __builtin_inff();
        int k1 = 0x7fffffff, k2 = 0x7fffffff;
        float xsum = 0.f;
        #pragma unroll
        for (int w = 0; w < 8; ++w) {
            P2 p = mb[w][tid];
            ins2(p.v1, p.k1, v1, k1, v2, k2);
            ins2(p.v2, p.k2, v1, k1, v2, k2);
            xsum += xs[w][tid];
        }
        P2 p; p.v1 = v1; p.k1 = k1; p.v2 = v2; p.k2 = k2;
        partials[Mtile * 64 + tid] = p;
        x2[Mtile * 64 + tid] = xsum;
    }
}

// ---------------- kernel 3: fused refine + loss + gather ----------------------
// Output flat position p uses the winner of query row sigma(p) (H/W swap).
#define MARGIN 0.05f
__global__ void scatter_merge_kernel(const P2* __restrict__ partials,
                                     const float* __restrict__ x2arr,
                                     const float* __restrict__ pq,
                                     const float* __restrict__ cb,
                                     double* __restrict__ lossAcc,
                                     float* __restrict__ out) {
    int ntile = blockIdx.x, b = blockIdx.y, tid = threadIdx.x;
    int wave = tid >> 6;
    __shared__ int idxs[64];
    __shared__ double lred[4];
    __shared__ float tile[64][65];

    double myloss = 0.0;
    if (tid < 64) {
        int p = ntile * 64 + tid;                       // output flat spatial pos
        int s = ((p & 63) << 6) | (p >> 6);             // sigma (involution)
        int row = (b << 12) | s;
        P2 pp = partials[row];
        float v1 = pp.v1, v2 = pp.v2;
        int k1 = pp.k1, k2 = pp.k2;
        int kwin = k1;
        double d2min;
        if (v2 - v1 < MARGIN) {
            const float* xp  = pq + (size_t)b * (C_ * N_) + s;
            const float* ca  = cb + (size_t)k1 * C_;
            const float* cbp = cb + (size_t)k2 * C_;
            double da = 0.0, db = 0.0;
            for (int c = 0; c < C_; ++c) {
                double xv = (double)xp[(size_t)c * N_];
                double ea = xv - (double)ca[c];  da += ea * ea;
                double eb = xv - (double)cbp[c]; db += eb * eb;
            }
            if (db < da || (db == da && k2 < k1)) { kwin = k2; d2min = db; }
            else d2min = da;
        } else {
            d2min = (double)(x2arr[row] + v1);
        }
        idxs[tid] = kwin;
        myloss = d2min;
    }
    double sd = myloss;
    #pragma unroll
    for (int off = 32; off; off >>= 1) sd += __shfl_down(sd, off);
    if ((tid & 63) == 0) lred[wave] = sd;
    __syncthreads();
    if (tid == 0) atomicAdd(lossAcc, lred[0] + lred[1] + lred[2] + lred[3]);

    for (int cc = 0; cc < 4; ++cc) {
        int c0 = cc * 64;
        #pragma unroll
        for (int pp = 0; pp < 16; ++pp) {
            int i = pp * 4 + (tid >> 6);
            int c = tid & 63;
            tile[i][c] = cb[(size_t)idxs[i] * C_ + c0 + c];   // coalesced rows
        }
        __syncthreads();
        #pragma unroll
        for (int pp = 0; pp < 16; ++pp) {
            int cl = pp * 4 + (tid >> 6);
            int nl = tid & 63;
            out[((size_t)(b * C_ + c0 + cl)) * N_ + ntile * 64 + nl] = tile[nl][cl];
        }
        __syncthreads();
    }
}

// ---------------- kernel 4: loss finalize ------------------------------------
__global__ void finalize_kernel(const double* __restrict__ lossAcc, float* __restrict__ out) {
    out[(size_t)B_ * C_ * N_] =
        (float)(1.25 * (*lossAcc) / (double)((size_t)B_ * N_ * C_));
}

// ---------------- launch ------------------------------------------------------
extern "C" void kernel_launch(void* const* d_in, const int* in_sizes, int n_in,
                              void* d_out, int out_size, void* d_ws, size_t ws_size,
                              hipStream_t stream) {
    const float* pq = (const float*)d_in[0];   // [16,256,64,64]
    const float* cb = (const float*)d_in[1];   // [512,256]
    float* out = (float*)d_out;                // 4194304 out + 1 loss
    char* ws = (char*)d_ws;
    double* lossAcc = (double*)ws;                            // 16 B
    float*  e2    = (float*)(ws + 16);                        // 2 KB
    float*  x2    = (float*)(ws + 16 + 2048);                 // 256 KB
    __bf16* Bpack = (__bf16*)(ws + 16 + 2048 + 262144);       // 512 KB
    P2* partials  = (P2*)(ws + 16 + 2048 + 262144 + 524288);  // 1 MB

    prep_kernel<<<K_, 64, 0, stream>>>(cb, e2, Bpack, lossAcc);
    main_kernel<<<1024, 512, 0, stream>>>(pq, Bpack, e2, partials, x2);
    scatter_merge_kernel<<<dim3(HW_, B_), 256, 0, stream>>>(partials, x2, pq, cb, lossAcc, out);
    finalize_kernel<<<1, 1, 0, stream>>>(lossAcc, out);
}